// Round 23
// baseline (180.181 us; speedup 1.0000x reference)
//
#include <hip/hip_runtime.h>
#include <hip/hip_fp16.h>
#include <float.h>

#define NN 100000
#define NE 1600000
#define IND 128
#define NH 4
#define TOT 64
#define NCOL 144                 // 64 h | 64 res | 4 al | 4 ar | 8 pad  (9 x 16)
#define BKT 782                  // ceil(NN/128): buckets of 128 dst nodes
#define STRIPES 8                // XCD stripes per bucket
#define CAPS 512                 // per (bucket,stripe) record capacity (mean 256, +16 sigma)
#define CHUNKF 8192              // edges per kbin-role block (long runs -> low write amp)
#define NBINF ((NE + CHUNKF - 1) / CHUNKF)   // 196
#define K1B 782                  // k1-role blocks (128 rows each)
#define STRIDE 2560              // records per bucket (mean 2048, +11 sigma)

typedef __attribute__((ext_vector_type(8))) short short8;
typedef __attribute__((ext_vector_type(4))) float f32x4;
typedef __attribute__((ext_vector_type(2))) __fp16 fp16x2;

__device__ __forceinline__ float lrelu(float a) { return a > 0.0f ? a : 0.2f * a; }

__device__ __forceinline__ unsigned short bf16_rne(float f) {
    unsigned u = __float_as_uint(f);
    unsigned r = u + 0x7FFFu + ((u >> 16) & 1u);
    return (unsigned short)(r >> 16);
}
__device__ __forceinline__ float bf16_to_f(unsigned short h) {
    return __uint_as_float(((unsigned)h) << 16);
}
__device__ __forceinline__ unsigned pack_h2(float a, float b) {
    fp16x2 h = __builtin_amdgcn_cvt_pkrtz(a, b);   // v_cvt_pkrtz_f16_f32
    return *(unsigned*)&h;
}
__device__ __forceinline__ float unpack_h(unsigned w, int hi) {
    unsigned short us = hi ? (unsigned short)(w >> 16) : (unsigned short)(w & 0xFFFF);
    __fp16 h = *(__fp16*)&us;
    return (float)h;
}
__device__ __forceinline__ float elu_fast(float a) {
    return a > 0.f ? a : __expf(a) - 1.f;   // hw v_exp vs ~35-inst expm1f
}

// K0: build bf16 weights in MFMA FRAGMENT ORDER:
// WTf[((ks*9 + nt)*64 + lk*16 + lr)*8 + j]  for k = ks*32 + lk*8 + j, c = nt*16 + lr.
__global__ void k0_wt(const float* __restrict__ lw, const float* __restrict__ lrw,
                      const float* __restrict__ attl, const float* __restrict__ attr,
                      unsigned short* __restrict__ WTf) {
    int idx = blockIdx.x * 256 + threadIdx.x;   // NCOL*128 = 18432
    if (idx >= NCOL * 128) return;
    int c = idx >> 7, k = idx & 127;
    float v = 0.f;
    if (c < 64) v = lw[k * 64 + c];
    else if (c < 128) v = lrw[k * 64 + (c - 64)];
    else if (c < 132) {
        int hh = c - 128; float s = 0.f;
        #pragma unroll
        for (int j = 0; j < 16; ++j) s += lw[k * 64 + hh * 16 + j] * attl[hh * 16 + j];
        v = s;
    } else if (c < 136) {
        int hh = c - 132; float s = 0.f;
        #pragma unroll
        for (int j = 0; j < 16; ++j) s += lw[k * 64 + hh * 16 + j] * attr[hh * 16 + j];
        v = s;
    }
    int nt = c >> 4, lr = c & 15;
    int ks = k >> 5, lk = (k >> 3) & 3, j = k & 7;
    WTf[(((ks * 9 + nt) * 64) + lk * 16 + lr) * 8 + j] = bf16_rne(v);
}

// k1bin: FUSED independent stages. Blocks [0,K1B): bf16 MFMA GEMM, 128 rows,
// fragment-ordered B, direct epilogue. Blocks [K1B,K1B+NBINF): edge binning
// with CHUNKF=8192 (mean run 10.5 records -> low write amplification).
__global__ __launch_bounds__(256) void k1bin(const float* __restrict__ x,
        const unsigned short* __restrict__ WTf,
        unsigned short* __restrict__ hbf, float* __restrict__ res,
        float* __restrict__ al, float* __restrict__ ar,
        const int* __restrict__ src, const int* __restrict__ dst,
        const float* __restrict__ ew,
        int* __restrict__ cursor, int2* __restrict__ tmp) {
    __shared__ __attribute__((aligned(16))) char smem[32768];
    int tid = threadIdx.x;

    if (blockIdx.x < K1B) {
        // ---------------- GEMM role ----------------
        unsigned short* Ahi = (unsigned short*)smem;   // 128x128 bf16, swizzled
        int lane = tid & 63;
        int wave = tid >> 6;
        int row0 = blockIdx.x * 128;
        int lr = lane & 15;     // A-row / B-col / C-col within tile
        int lk = lane >> 4;     // k-group (0..3)

        #pragma unroll
        for (int it = 0; it < 16; ++it) {
            int i = it * 256 + tid;          // 0..4095 float4-chunks
            int r = i >> 5;                  // 0..127
            int c4 = (i & 31) << 2;          // col 0,4,...,124
            int grow = row0 + r;
            float4 v = make_float4(0.f, 0.f, 0.f, 0.f);
            if (grow < NN) v = *(const float4*)(x + (size_t)grow * IND + c4);
            unsigned hi01 = (unsigned)bf16_rne(v.x) | ((unsigned)bf16_rne(v.y) << 16);
            unsigned hi23 = (unsigned)bf16_rne(v.z) | ((unsigned)bf16_rne(v.w) << 16);
            int swg = (c4 >> 3) ^ (r & 15);                // 4-bit swizzled 16B granule
            int sidx = r * 128 + swg * 8 + (c4 & 4);       // in shorts
            *(uint2*)(&Ahi[sidx]) = make_uint2(hi01, hi23);
        }
        __syncthreads();

        f32x4 acc[2][9];
        #pragma unroll
        for (int mt = 0; mt < 2; ++mt)
            #pragma unroll
            for (int nt = 0; nt < 9; ++nt) acc[mt][nt] = (f32x4)(0.f);

        #pragma unroll
        for (int ks = 0; ks < 4; ++ks) {
            short8 bh[9];
            #pragma unroll
            for (int nt = 0; nt < 9; ++nt)
                bh[nt] = *(const short8*)(WTf + (((ks * 9 + nt) << 6) + lane) * 8);  // coalesced 1KB
            #pragma unroll
            for (int mt = 0; mt < 2; ++mt) {
                int arow = wave * 32 + mt * 16 + lr;
                int swg = (ks * 4 + lk) ^ lr;              // arow&15 == lr
                short8 ah = *(const short8*)(&Ahi[arow * 128 + swg * 8]);
                #pragma unroll
                for (int nt = 0; nt < 9; ++nt)
                    acc[mt][nt] = __builtin_amdgcn_mfma_f32_16x16x32_bf16(ah, bh[nt], acc[mt][nt], 0, 0, 0);
            }
        }
        #pragma unroll
        for (int mt = 0; mt < 2; ++mt) {
            #pragma unroll
            for (int nt = 0; nt < 9; ++nt) {
                int c = nt * 16 + lr;
                #pragma unroll
                for (int r = 0; r < 4; ++r) {
                    int row = row0 + wave * 32 + mt * 16 + lk * 4 + r;
                    if (row >= NN) continue;
                    float v = acc[mt][nt][r];
                    if (c < 64)       hbf[(size_t)row * TOT + c] = bf16_rne(v);
                    else if (c < 128) res[(size_t)row * TOT + (c - 64)] = v;
                    else if (c < 132) al[(size_t)row * 4 + (c - 128)] = v;
                    else if (c < 136) ar[(size_t)row * 4 + (c - 132)] = v;
                }
            }
        }
    } else {
        // ---------------- binning role ----------------
        int* hist = (int*)smem;          // BKT ints
        int* lcur = hist + BKT;          // BKT ints (total 6.3KB)
        int cb = blockIdx.x - K1B;
        int stripe = cb & 7;
        int e0 = cb * CHUNKF;
        for (int i = tid; i < BKT; i += 256) hist[i] = 0;
        __syncthreads();
        for (int i = tid; i < CHUNKF; i += 256) {
            int e = e0 + i;
            if (e < NE) atomicAdd(&hist[dst[e] >> 7], 1);
        }
        __syncthreads();
        for (int b = tid; b < BKT; b += 256) {
            int c = hist[b];
            lcur[b] = (c > 0) ? atomicAdd(cursor + b * STRIPES + stripe, c) : 0;
        }
        __syncthreads();
        for (int i = tid; i < CHUNKF; i += 256) {
            int e = e0 + i;
            if (e >= NE) continue;
            int d = dst[e];
            int b = d >> 7;
            int pos = atomicAdd(&lcur[b], 1);
            if (pos < CAPS)
                tmp[(size_t)(b * STRIPES + stripe) * CAPS + pos] =
                    make_int2(src[e] | ((d & 127) << 20), __float_as_int(ew[e]));
        }
    }
}

// kpagg: FUSED permute + aggregate, one block per 128-node bucket, 512 threads.
// Aggregate uses 16 SLOTS x 4 PARTS: each record handled by 4 lanes x 32B
// (2 uint4 loads) -> 32 outstanding gathers/wave (was 8). head == part.
__global__ __launch_bounds__(512) void kpagg(const int* __restrict__ cursor,
                                             const int2* __restrict__ tmp,
                                             const float* __restrict__ al,
                                             const float* __restrict__ ar,
                                             const unsigned short* __restrict__ hbf,
                                             float* __restrict__ out) {
    __shared__ int hist[129];
    __shared__ int cur[128];
    __shared__ int ns[8];
    __shared__ float4 arl[128];
    __shared__ int lrecS[STRIDE];
    __shared__ unsigned lrecC[STRIDE * 2];
    int tid = threadIdx.x;
    int b = blockIdx.x;
    int node0 = b * 128;

    if (tid < 129) hist[tid] = 0;
    if (tid < 8) ns[tid] = min(cursor[b * STRIPES + tid], CAPS);
    if (tid >= 128 && tid < 256) {
        int l = tid - 128;
        int node = node0 + l;
        arl[l] = (node < NN) ? *(const float4*)(ar + (size_t)node * 4)
                             : make_float4(0.f, 0.f, 0.f, 0.f);
    }
    __syncthreads();

    const int2* tb = tmp + (size_t)b * STRIPES * CAPS;
    for (int j = tid; j < STRIPES * CAPS; j += 512) {
        int s8 = j >> 9;              // CAPS = 512
        int i = j & (CAPS - 1);
        if (i < ns[s8])
            atomicAdd(&hist[(((unsigned)tb[(size_t)s8 * CAPS + i].x) >> 20) + 1], 1);
    }
    __syncthreads();
    for (int off = 1; off < 129; off <<= 1) {
        int v = 0;
        if (tid < 129 && tid >= off) v = hist[tid - off];
        __syncthreads();
        if (tid < 129) hist[tid] += v;
        __syncthreads();
    }
    if (tid < 128) cur[tid] = hist[tid];
    __syncthreads();

    for (int j = tid; j < STRIPES * CAPS; j += 512) {
        int s8 = j >> 9;
        int i = j & (CAPS - 1);
        if (i >= ns[s8]) continue;
        int2 r = tb[(size_t)s8 * CAPS + i];
        int s = r.x & 0xFFFFF;
        int dlo = ((unsigned)r.x) >> 20;
        float w = __int_as_float(r.y);
        float4 a4 = *(const float4*)(al + (size_t)s * 4);   // L2-resident (1.6MB)
        float4 b4 = arl[dlo];
        float c0 = __expf(lrelu(w * (a4.x + b4.x)));
        float c1 = __expf(lrelu(w * (a4.y + b4.y)));
        float c2 = __expf(lrelu(w * (a4.z + b4.z)));
        float c3 = __expf(lrelu(w * (a4.w + b4.w)));
        int pos = atomicAdd(&cur[dlo], 1);
        if (pos < STRIDE) {
            lrecS[pos] = s;
            lrecC[pos * 2 + 0] = pack_h2(c0, c1);
            lrecC[pos * 2 + 1] = pack_h2(c2, c3);
        }
    }
    __syncthreads();

    // aggregate: 8 waves x 16 nodes each; per wave: 16 record-slots x 4 parts.
    // part == head; lane covers cols part*16 .. part*16+15 (32B = 2 uint4).
    int wave = tid >> 6;
    int lane = tid & 63;
    int slot = lane >> 2;     // 0..15: record in flight
    int part = lane & 3;      // head index; 16 cols per lane
    int cwo = part >> 1;
    int hi = part & 1;
    for (int rr = 0; rr < 16; ++rr) {
        int dlo = wave * 16 + rr;
        int node = node0 + dlo;
        if (node >= NN) break;
        int beg = hist[dlo];
        int end = min(hist[dlo + 1], STRIDE);
        beg = min(beg, end);

        float4 a0 = make_float4(0.f, 0.f, 0.f, 0.f);
        float4 a1 = a0, a2 = a0, a3 = a0;
        float den = 0.f;
        for (int p = beg + slot; p < end; p += 16) {
            int s = lrecS[p];
            float c = unpack_h(lrecC[p * 2 + cwo], hi);
            den += c;
            const unsigned short* hp = hbf + (size_t)s * TOT + part * 16;
            uint4 u0 = *(const uint4*)hp;          // cols 0..7 of this head
            uint4 u1 = *(const uint4*)(hp + 8);    // cols 8..15
            a0.x = fmaf(__uint_as_float(u0.x << 16),          c, a0.x);
            a0.y = fmaf(__uint_as_float(u0.x & 0xFFFF0000u),  c, a0.y);
            a0.z = fmaf(__uint_as_float(u0.y << 16),          c, a0.z);
            a0.w = fmaf(__uint_as_float(u0.y & 0xFFFF0000u),  c, a0.w);
            a1.x = fmaf(__uint_as_float(u0.z << 16),          c, a1.x);
            a1.y = fmaf(__uint_as_float(u0.z & 0xFFFF0000u),  c, a1.y);
            a1.z = fmaf(__uint_as_float(u0.w << 16),          c, a1.z);
            a1.w = fmaf(__uint_as_float(u0.w & 0xFFFF0000u),  c, a1.w);
            a2.x = fmaf(__uint_as_float(u1.x << 16),          c, a2.x);
            a2.y = fmaf(__uint_as_float(u1.x & 0xFFFF0000u),  c, a2.y);
            a2.z = fmaf(__uint_as_float(u1.y << 16),          c, a2.z);
            a2.w = fmaf(__uint_as_float(u1.y & 0xFFFF0000u),  c, a2.w);
            a3.x = fmaf(__uint_as_float(u1.z << 16),          c, a3.x);
            a3.y = fmaf(__uint_as_float(u1.z & 0xFFFF0000u),  c, a3.y);
            a3.z = fmaf(__uint_as_float(u1.w << 16),          c, a3.z);
            a3.w = fmaf(__uint_as_float(u1.w & 0xFFFF0000u),  c, a3.w);
        }
        // reduce over the 16 slots (lane xor 4, 8, 16, 32)
        #pragma unroll
        for (int off = 4; off <= 32; off <<= 1) {
            a0.x += __shfl_xor(a0.x, off); a0.y += __shfl_xor(a0.y, off);
            a0.z += __shfl_xor(a0.z, off); a0.w += __shfl_xor(a0.w, off);
            a1.x += __shfl_xor(a1.x, off); a1.y += __shfl_xor(a1.y, off);
            a1.z += __shfl_xor(a1.z, off); a1.w += __shfl_xor(a1.w, off);
            a2.x += __shfl_xor(a2.x, off); a2.y += __shfl_xor(a2.y, off);
            a2.z += __shfl_xor(a2.z, off); a2.w += __shfl_xor(a2.w, off);
            a3.x += __shfl_xor(a3.x, off); a3.y += __shfl_xor(a3.y, off);
            a3.z += __shfl_xor(a3.z, off); a3.w += __shfl_xor(a3.w, off);
            den  += __shfl_xor(den, off);
        }
        if (slot == 0) {
            float rinv = (den > 0.f) ? 1.f / den : 0.f;
            float* op = out + (size_t)node * TOT + part * 16;
            float4 r0 = *(const float4*)op;
            float4 r1 = *(const float4*)(op + 4);
            float4 r2 = *(const float4*)(op + 8);
            float4 r3 = *(const float4*)(op + 12);
            float4 o0, o1, o2, o3;
            o0.x = elu_fast(a0.x * rinv) + r0.x;
            o0.y = elu_fast(a0.y * rinv) + r0.y;
            o0.z = elu_fast(a0.z * rinv) + r0.z;
            o0.w = elu_fast(a0.w * rinv) + r0.w;
            o1.x = elu_fast(a1.x * rinv) + r1.x;
            o1.y = elu_fast(a1.y * rinv) + r1.y;
            o1.z = elu_fast(a1.z * rinv) + r1.z;
            o1.w = elu_fast(a1.w * rinv) + r1.w;
            o2.x = elu_fast(a2.x * rinv) + r2.x;
            o2.y = elu_fast(a2.y * rinv) + r2.y;
            o2.z = elu_fast(a2.z * rinv) + r2.z;
            o2.w = elu_fast(a2.w * rinv) + r2.w;
            o3.x = elu_fast(a3.x * rinv) + r3.x;
            o3.y = elu_fast(a3.y * rinv) + r3.y;
            o3.z = elu_fast(a3.z * rinv) + r3.z;
            o3.w = elu_fast(a3.w * rinv) + r3.w;
            *(float4*)op = o0;
            *(float4*)(op + 4) = o1;
            *(float4*)(op + 8) = o2;
            *(float4*)(op + 12) = o3;
        }
    }
}

extern "C" void kernel_launch(void* const* d_in, const int* in_sizes, int n_in,
                              void* d_out, int out_size, void* d_ws, size_t ws_size,
                              hipStream_t stream) {
    const float* x    = (const float*)d_in[0];
    const int*   ei   = (const int*)d_in[1];
    const float* ew   = (const float*)d_in[2];
    const float* lw   = (const float*)d_in[3];
    const float* attl = (const float*)d_in[4];
    const float* attr = (const float*)d_in[5];
    const float* lrw  = (const float*)d_in[6];
    float* out = (float*)d_out;
    const int* src = ei;
    const int* dst = ei + NE;

    char* w = (char*)d_ws;
    auto alloc = [&](size_t bytes) { char* p = w; w += (bytes + 255) & ~(size_t)255; return p; };
    unsigned short* WTf = (unsigned short*)alloc((size_t)NCOL * 128 * 2);
    unsigned short* hbf = (unsigned short*)alloc((size_t)NN * TOT * 2);
    float* al      = (float*)alloc((size_t)NN * 4 * 4);
    float* ar      = (float*)alloc((size_t)NN * 4 * 4);
    int*   cursor  = (int*)alloc((size_t)BKT * STRIPES * 4);
    int2*  tmp     = (int2*)alloc((size_t)BKT * STRIPES * CAPS * 8);
    size_t needed = (size_t)(w - (char*)d_ws);
    if (ws_size < needed) return;  // fail loudly (validation will catch)

    hipMemsetAsync(cursor, 0, (size_t)BKT * STRIPES * 4, stream);

    k0_wt<<<(NCOL * 128 + 255) / 256, 256, 0, stream>>>(lw, lrw, attl, attr, WTf);
    k1bin<<<K1B + NBINF, 256, 0, stream>>>(x, WTf, hbf, out, al, ar,
                                           src, dst, ew, cursor, tmp);
    kpagg<<<BKT, 512, 0, stream>>>(cursor, tmp, al, ar, hbf, out);
}

// Round 24
// 129.027 us; speedup vs baseline: 1.3965x; 1.3965x over previous
//
#include <hip/hip_runtime.h>
#include <hip/hip_fp16.h>
#include <float.h>

#define NN 100000
#define NE 1600000
#define IND 128
#define NH 4
#define TOT 64
#define NCOL 144                 // 64 h | 64 res | 4 al | 4 ar | 8 pad  (9 x 16)
#define BKT 782                  // ceil(NN/128): buckets of 128 dst nodes
#define STRIPES 8                // XCD stripes per bucket
#define CAPS 512                 // per (bucket,stripe) record capacity (mean 256, +16 sigma)
#define CHUNKF 8192              // edges per kbin-role block (long runs -> low write amp)
#define NBINF ((NE + CHUNKF - 1) / CHUNKF)   // 196
#define K1B 782                  // k1-role blocks (128 rows each)
#define STRIDE 2560              // records per bucket (mean 2048, +11 sigma)

typedef __attribute__((ext_vector_type(8))) short short8;
typedef __attribute__((ext_vector_type(4))) float f32x4;
typedef __attribute__((ext_vector_type(2))) __fp16 fp16x2;

__device__ __forceinline__ float lrelu(float a) { return a > 0.0f ? a : 0.2f * a; }

__device__ __forceinline__ unsigned short bf16_rne(float f) {
    unsigned u = __float_as_uint(f);
    unsigned r = u + 0x7FFFu + ((u >> 16) & 1u);
    return (unsigned short)(r >> 16);
}
__device__ __forceinline__ float bf16_to_f(unsigned short h) {
    return __uint_as_float(((unsigned)h) << 16);
}
__device__ __forceinline__ unsigned pack_h2(float a, float b) {
    fp16x2 h = __builtin_amdgcn_cvt_pkrtz(a, b);   // v_cvt_pkrtz_f16_f32
    return *(unsigned*)&h;
}
__device__ __forceinline__ float unpack_h(unsigned w, int hi) {
    unsigned short us = hi ? (unsigned short)(w >> 16) : (unsigned short)(w & 0xFFFF);
    __fp16 h = *(__fp16*)&us;
    return (float)h;
}
__device__ __forceinline__ float elu_fast(float a) {
    return a > 0.f ? a : __expf(a) - 1.f;   // hw v_exp vs ~35-inst expm1f
}

// K0: build bf16 weights in MFMA FRAGMENT ORDER:
// WTf[((ks*9 + nt)*64 + lk*16 + lr)*8 + j]  for k = ks*32 + lk*8 + j, c = nt*16 + lr.
__global__ void k0_wt(const float* __restrict__ lw, const float* __restrict__ lrw,
                      const float* __restrict__ attl, const float* __restrict__ attr,
                      unsigned short* __restrict__ WTf) {
    int idx = blockIdx.x * 256 + threadIdx.x;   // NCOL*128 = 18432
    if (idx >= NCOL * 128) return;
    int c = idx >> 7, k = idx & 127;
    float v = 0.f;
    if (c < 64) v = lw[k * 64 + c];
    else if (c < 128) v = lrw[k * 64 + (c - 64)];
    else if (c < 132) {
        int hh = c - 128; float s = 0.f;
        #pragma unroll
        for (int j = 0; j < 16; ++j) s += lw[k * 64 + hh * 16 + j] * attl[hh * 16 + j];
        v = s;
    } else if (c < 136) {
        int hh = c - 132; float s = 0.f;
        #pragma unroll
        for (int j = 0; j < 16; ++j) s += lw[k * 64 + hh * 16 + j] * attr[hh * 16 + j];
        v = s;
    }
    int nt = c >> 4, lr = c & 15;
    int ks = k >> 5, lk = (k >> 3) & 3, j = k & 7;
    WTf[(((ks * 9 + nt) * 64) + lk * 16 + lr) * 8 + j] = bf16_rne(v);
}

// k1bin: FUSED independent stages. Blocks [0,K1B): bf16 MFMA GEMM, 128 rows,
// fragment-ordered B, direct epilogue. Blocks [K1B,K1B+NBINF): edge binning
// with CHUNKF=8192 (mean run 10.5 records -> low write amplification).
__global__ __launch_bounds__(256) void k1bin(const float* __restrict__ x,
        const unsigned short* __restrict__ WTf,
        unsigned short* __restrict__ hbf, float* __restrict__ res,
        float* __restrict__ al, float* __restrict__ ar,
        const int* __restrict__ src, const int* __restrict__ dst,
        const float* __restrict__ ew,
        int* __restrict__ cursor, int2* __restrict__ tmp) {
    __shared__ __attribute__((aligned(16))) char smem[32768];
    int tid = threadIdx.x;

    if (blockIdx.x < K1B) {
        // ---------------- GEMM role ----------------
        unsigned short* Ahi = (unsigned short*)smem;   // 128x128 bf16, swizzled
        int lane = tid & 63;
        int wave = tid >> 6;
        int row0 = blockIdx.x * 128;
        int lr = lane & 15;     // A-row / B-col / C-col within tile
        int lk = lane >> 4;     // k-group (0..3)

        #pragma unroll
        for (int it = 0; it < 16; ++it) {
            int i = it * 256 + tid;          // 0..4095 float4-chunks
            int r = i >> 5;                  // 0..127
            int c4 = (i & 31) << 2;          // col 0,4,...,124
            int grow = row0 + r;
            float4 v = make_float4(0.f, 0.f, 0.f, 0.f);
            if (grow < NN) v = *(const float4*)(x + (size_t)grow * IND + c4);
            unsigned hi01 = (unsigned)bf16_rne(v.x) | ((unsigned)bf16_rne(v.y) << 16);
            unsigned hi23 = (unsigned)bf16_rne(v.z) | ((unsigned)bf16_rne(v.w) << 16);
            int swg = (c4 >> 3) ^ (r & 15);                // 4-bit swizzled 16B granule
            int sidx = r * 128 + swg * 8 + (c4 & 4);       // in shorts
            *(uint2*)(&Ahi[sidx]) = make_uint2(hi01, hi23);
        }
        __syncthreads();

        f32x4 acc[2][9];
        #pragma unroll
        for (int mt = 0; mt < 2; ++mt)
            #pragma unroll
            for (int nt = 0; nt < 9; ++nt) acc[mt][nt] = (f32x4)(0.f);

        #pragma unroll
        for (int ks = 0; ks < 4; ++ks) {
            short8 bh[9];
            #pragma unroll
            for (int nt = 0; nt < 9; ++nt)
                bh[nt] = *(const short8*)(WTf + (((ks * 9 + nt) << 6) + lane) * 8);  // coalesced 1KB
            #pragma unroll
            for (int mt = 0; mt < 2; ++mt) {
                int arow = wave * 32 + mt * 16 + lr;
                int swg = (ks * 4 + lk) ^ lr;              // arow&15 == lr
                short8 ah = *(const short8*)(&Ahi[arow * 128 + swg * 8]);
                #pragma unroll
                for (int nt = 0; nt < 9; ++nt)
                    acc[mt][nt] = __builtin_amdgcn_mfma_f32_16x16x32_bf16(ah, bh[nt], acc[mt][nt], 0, 0, 0);
            }
        }
        #pragma unroll
        for (int mt = 0; mt < 2; ++mt) {
            #pragma unroll
            for (int nt = 0; nt < 9; ++nt) {
                int c = nt * 16 + lr;
                #pragma unroll
                for (int r = 0; r < 4; ++r) {
                    int row = row0 + wave * 32 + mt * 16 + lk * 4 + r;
                    if (row >= NN) continue;
                    float v = acc[mt][nt][r];
                    if (c < 64)       hbf[(size_t)row * TOT + c] = bf16_rne(v);
                    else if (c < 128) res[(size_t)row * TOT + (c - 64)] = v;
                    else if (c < 132) al[(size_t)row * 4 + (c - 128)] = v;
                    else if (c < 136) ar[(size_t)row * 4 + (c - 132)] = v;
                }
            }
        }
    } else {
        // ---------------- binning role ----------------
        int* hist = (int*)smem;          // BKT ints
        int* lcur = hist + BKT;          // BKT ints (total 6.3KB)
        int cb = blockIdx.x - K1B;
        int stripe = cb & 7;
        int e0 = cb * CHUNKF;
        for (int i = tid; i < BKT; i += 256) hist[i] = 0;
        __syncthreads();
        for (int i = tid; i < CHUNKF; i += 256) {
            int e = e0 + i;
            if (e < NE) atomicAdd(&hist[dst[e] >> 7], 1);
        }
        __syncthreads();
        for (int b = tid; b < BKT; b += 256) {
            int c = hist[b];
            lcur[b] = (c > 0) ? atomicAdd(cursor + b * STRIPES + stripe, c) : 0;
        }
        __syncthreads();
        for (int i = tid; i < CHUNKF; i += 256) {
            int e = e0 + i;
            if (e >= NE) continue;
            int d = dst[e];
            int b = d >> 7;
            int pos = atomicAdd(&lcur[b], 1);
            if (pos < CAPS)
                tmp[(size_t)(b * STRIPES + stripe) * CAPS + pos] =
                    make_int2(src[e] | ((d & 127) << 20), __float_as_int(ew[e]));
        }
    }
}

// kpagg: FUSED permute + aggregate, one block per 128-node bucket, 512 threads.
// Aggregate: 8 waves x 16 nodes; per wave 8 record-slots x 8 parts (round-22
// proven form: one uint4/lane/record).
__global__ __launch_bounds__(512) void kpagg(const int* __restrict__ cursor,
                                             const int2* __restrict__ tmp,
                                             const float* __restrict__ al,
                                             const float* __restrict__ ar,
                                             const unsigned short* __restrict__ hbf,
                                             float* __restrict__ out) {
    __shared__ int hist[129];
    __shared__ int cur[128];
    __shared__ int ns[8];
    __shared__ float4 arl[128];
    __shared__ int lrecS[STRIDE];
    __shared__ unsigned lrecC[STRIDE * 2];
    int tid = threadIdx.x;
    int b = blockIdx.x;
    int node0 = b * 128;

    if (tid < 129) hist[tid] = 0;
    if (tid < 8) ns[tid] = min(cursor[b * STRIPES + tid], CAPS);
    if (tid >= 128 && tid < 256) {
        int l = tid - 128;
        int node = node0 + l;
        arl[l] = (node < NN) ? *(const float4*)(ar + (size_t)node * 4)
                             : make_float4(0.f, 0.f, 0.f, 0.f);
    }
    __syncthreads();

    const int2* tb = tmp + (size_t)b * STRIPES * CAPS;
    for (int j = tid; j < STRIPES * CAPS; j += 512) {
        int s8 = j >> 9;              // CAPS = 512
        int i = j & (CAPS - 1);
        if (i < ns[s8])
            atomicAdd(&hist[(((unsigned)tb[(size_t)s8 * CAPS + i].x) >> 20) + 1], 1);
    }
    __syncthreads();
    for (int off = 1; off < 129; off <<= 1) {
        int v = 0;
        if (tid < 129 && tid >= off) v = hist[tid - off];
        __syncthreads();
        if (tid < 129) hist[tid] += v;
        __syncthreads();
    }
    if (tid < 128) cur[tid] = hist[tid];
    __syncthreads();

    for (int j = tid; j < STRIPES * CAPS; j += 512) {
        int s8 = j >> 9;
        int i = j & (CAPS - 1);
        if (i >= ns[s8]) continue;
        int2 r = tb[(size_t)s8 * CAPS + i];
        int s = r.x & 0xFFFFF;
        int dlo = ((unsigned)r.x) >> 20;
        float w = __int_as_float(r.y);
        float4 a4 = *(const float4*)(al + (size_t)s * 4);   // L2-resident (1.6MB)
        float4 b4 = arl[dlo];
        float c0 = __expf(lrelu(w * (a4.x + b4.x)));
        float c1 = __expf(lrelu(w * (a4.y + b4.y)));
        float c2 = __expf(lrelu(w * (a4.z + b4.z)));
        float c3 = __expf(lrelu(w * (a4.w + b4.w)));
        int pos = atomicAdd(&cur[dlo], 1);
        if (pos < STRIDE) {
            lrecS[pos] = s;
            lrecC[pos * 2 + 0] = pack_h2(c0, c1);
            lrecC[pos * 2 + 1] = pack_h2(c2, c3);
        }
    }
    __syncthreads();

    // aggregate: 8 waves x 16 nodes each; per wave: 8 record-slots x 8 parts
    int wave = tid >> 6;
    int lane = tid & 63;
    int slot = lane >> 3;
    int part = lane & 7;
    int head = part >> 1;
    int cwo = head >> 1;
    for (int rr = 0; rr < 16; ++rr) {
        int dlo = wave * 16 + rr;
        int node = node0 + dlo;
        if (node >= NN) break;
        int beg = hist[dlo];
        int end = min(hist[dlo + 1], STRIDE);
        beg = min(beg, end);

        float4 acc0 = make_float4(0.f, 0.f, 0.f, 0.f);
        float4 acc1 = make_float4(0.f, 0.f, 0.f, 0.f);
        float den = 0.f;
        for (int p = beg + slot; p < end; p += 8) {
            int s = lrecS[p];
            unsigned cw = lrecC[p * 2 + cwo];
            float c = unpack_h(cw, head & 1);
            den += c;
            uint4 u = *(const uint4*)(hbf + (size_t)s * TOT + part * 8);  // 8 lanes = 128B line
            acc0.x = fmaf(__uint_as_float(u.x << 16),          c, acc0.x);
            acc0.y = fmaf(__uint_as_float(u.x & 0xFFFF0000u),  c, acc0.y);
            acc0.z = fmaf(__uint_as_float(u.y << 16),          c, acc0.z);
            acc0.w = fmaf(__uint_as_float(u.y & 0xFFFF0000u),  c, acc0.w);
            acc1.x = fmaf(__uint_as_float(u.z << 16),          c, acc1.x);
            acc1.y = fmaf(__uint_as_float(u.z & 0xFFFF0000u),  c, acc1.y);
            acc1.z = fmaf(__uint_as_float(u.w << 16),          c, acc1.z);
            acc1.w = fmaf(__uint_as_float(u.w & 0xFFFF0000u),  c, acc1.w);
        }
        #pragma unroll
        for (int off = 8; off <= 32; off <<= 1) {
            acc0.x += __shfl_xor(acc0.x, off);
            acc0.y += __shfl_xor(acc0.y, off);
            acc0.z += __shfl_xor(acc0.z, off);
            acc0.w += __shfl_xor(acc0.w, off);
            acc1.x += __shfl_xor(acc1.x, off);
            acc1.y += __shfl_xor(acc1.y, off);
            acc1.z += __shfl_xor(acc1.z, off);
            acc1.w += __shfl_xor(acc1.w, off);
            den    += __shfl_xor(den, off);
        }
        if (slot == 0) {
            float rinv = (den > 0.f) ? 1.f / den : 0.f;
            float* op = out + (size_t)node * TOT + part * 8;
            float4 r0 = *(const float4*)op;
            float4 r1 = *(const float4*)(op + 4);
            float4 o0, o1;
            o0.x = elu_fast(acc0.x * rinv) + r0.x;
            o0.y = elu_fast(acc0.y * rinv) + r0.y;
            o0.z = elu_fast(acc0.z * rinv) + r0.z;
            o0.w = elu_fast(acc0.w * rinv) + r0.w;
            o1.x = elu_fast(acc1.x * rinv) + r1.x;
            o1.y = elu_fast(acc1.y * rinv) + r1.y;
            o1.z = elu_fast(acc1.z * rinv) + r1.z;
            o1.w = elu_fast(acc1.w * rinv) + r1.w;
            *(float4*)op = o0;
            *(float4*)(op + 4) = o1;
        }
    }
}

extern "C" void kernel_launch(void* const* d_in, const int* in_sizes, int n_in,
                              void* d_out, int out_size, void* d_ws, size_t ws_size,
                              hipStream_t stream) {
    const float* x    = (const float*)d_in[0];
    const int*   ei   = (const int*)d_in[1];
    const float* ew   = (const float*)d_in[2];
    const float* lw   = (const float*)d_in[3];
    const float* attl = (const float*)d_in[4];
    const float* attr = (const float*)d_in[5];
    const float* lrw  = (const float*)d_in[6];
    float* out = (float*)d_out;
    const int* src = ei;
    const int* dst = ei + NE;

    char* w = (char*)d_ws;
    auto alloc = [&](size_t bytes) { char* p = w; w += (bytes + 255) & ~(size_t)255; return p; };
    unsigned short* WTf = (unsigned short*)alloc((size_t)NCOL * 128 * 2);
    unsigned short* hbf = (unsigned short*)alloc((size_t)NN * TOT * 2);
    float* al      = (float*)alloc((size_t)NN * 4 * 4);
    float* ar      = (float*)alloc((size_t)NN * 4 * 4);
    int*   cursor  = (int*)alloc((size_t)BKT * STRIPES * 4);
    int2*  tmp     = (int2*)alloc((size_t)BKT * STRIPES * CAPS * 8);
    size_t needed = (size_t)(w - (char*)d_ws);
    if (ws_size < needed) return;  // fail loudly (validation will catch)

    hipMemsetAsync(cursor, 0, (size_t)BKT * STRIPES * 4, stream);

    k0_wt<<<(NCOL * 128 + 255) / 256, 256, 0, stream>>>(lw, lrw, attl, attr, WTf);
    k1bin<<<K1B + NBINF, 256, 0, stream>>>(x, WTf, hbf, out, al, ar,
                                           src, dst, ew, cursor, tmp);
    kpagg<<<BKT, 512, 0, stream>>>(cursor, tmp, al, ar, hbf, out);
}

// Round 25
// 122.607 us; speedup vs baseline: 1.4696x; 1.0524x over previous
//
#include <hip/hip_runtime.h>
#include <hip/hip_fp16.h>
#include <float.h>

#define NN 100000
#define NE 1600000
#define IND 128
#define NH 4
#define TOT 64
#define NCOL 144                 // 64 h | 64 res | 4 al | 4 ar | 8 pad  (9 x 16)
#define BKT 1563                 // ceil(NN/64): buckets of 64 dst nodes
#define STRIPES 8                // XCD stripes per bucket
#define CAPS 256                 // per (bucket,stripe) record capacity (mean 128, +11 sigma)
#define CHUNKF 4096              // edges per kbin-role block (391 blocks hide under GEMM)
#define NBINF ((NE + CHUNKF - 1) / CHUNKF)   // 391
#define K1B 782                  // k1-role blocks (128 rows each)
#define STRIDE 1280              // records per bucket (mean 1024, +8 sigma)

typedef __attribute__((ext_vector_type(8))) short short8;
typedef __attribute__((ext_vector_type(4))) float f32x4;
typedef __attribute__((ext_vector_type(2))) __fp16 fp16x2;

__device__ __forceinline__ float lrelu(float a) { return a > 0.0f ? a : 0.2f * a; }

__device__ __forceinline__ unsigned short bf16_rne(float f) {
    unsigned u = __float_as_uint(f);
    unsigned r = u + 0x7FFFu + ((u >> 16) & 1u);
    return (unsigned short)(r >> 16);
}
__device__ __forceinline__ float bf16_to_f(unsigned short h) {
    return __uint_as_float(((unsigned)h) << 16);
}
__device__ __forceinline__ unsigned pack_h2(float a, float b) {
    fp16x2 h = __builtin_amdgcn_cvt_pkrtz(a, b);   // v_cvt_pkrtz_f16_f32
    return *(unsigned*)&h;
}
__device__ __forceinline__ float unpack_h(unsigned w, int hi) {
    unsigned short us = hi ? (unsigned short)(w >> 16) : (unsigned short)(w & 0xFFFF);
    __fp16 h = *(__fp16*)&us;
    return (float)h;
}
__device__ __forceinline__ float elu_fast(float a) {
    return a > 0.f ? a : __expf(a) - 1.f;   // hw v_exp vs ~35-inst expm1f
}

// K0: build bf16 weights in MFMA FRAGMENT ORDER:
// WTf[((ks*9 + nt)*64 + lk*16 + lr)*8 + j]  for k = ks*32 + lk*8 + j, c = nt*16 + lr.
__global__ void k0_wt(const float* __restrict__ lw, const float* __restrict__ lrw,
                      const float* __restrict__ attl, const float* __restrict__ attr,
                      unsigned short* __restrict__ WTf) {
    int idx = blockIdx.x * 256 + threadIdx.x;   // NCOL*128 = 18432
    if (idx >= NCOL * 128) return;
    int c = idx >> 7, k = idx & 127;
    float v = 0.f;
    if (c < 64) v = lw[k * 64 + c];
    else if (c < 128) v = lrw[k * 64 + (c - 64)];
    else if (c < 132) {
        int hh = c - 128; float s = 0.f;
        #pragma unroll
        for (int j = 0; j < 16; ++j) s += lw[k * 64 + hh * 16 + j] * attl[hh * 16 + j];
        v = s;
    } else if (c < 136) {
        int hh = c - 132; float s = 0.f;
        #pragma unroll
        for (int j = 0; j < 16; ++j) s += lw[k * 64 + hh * 16 + j] * attr[hh * 16 + j];
        v = s;
    }
    int nt = c >> 4, lr = c & 15;
    int ks = k >> 5, lk = (k >> 3) & 3, j = k & 7;
    WTf[(((ks * 9 + nt) * 64) + lk * 16 + lr) * 8 + j] = bf16_rne(v);
}

// k1bin: FUSED independent stages. Blocks [0,K1B): bf16 MFMA GEMM, 128 rows,
// fragment-ordered B, direct epilogue (round-22 proven 73.5us form).
// Blocks [K1B,K1B+NBINF): edge binning into 1563 64-node buckets, CHUNKF=4096.
__global__ __launch_bounds__(256) void k1bin(const float* __restrict__ x,
        const unsigned short* __restrict__ WTf,
        unsigned short* __restrict__ hbf, float* __restrict__ res,
        float* __restrict__ al, float* __restrict__ ar,
        const int* __restrict__ src, const int* __restrict__ dst,
        const float* __restrict__ ew,
        int* __restrict__ cursor, int2* __restrict__ tmp) {
    __shared__ __attribute__((aligned(16))) char smem[32768];
    int tid = threadIdx.x;

    if (blockIdx.x < K1B) {
        // ---------------- GEMM role ----------------
        unsigned short* Ahi = (unsigned short*)smem;   // 128x128 bf16, swizzled
        int lane = tid & 63;
        int wave = tid >> 6;
        int row0 = blockIdx.x * 128;
        int lr = lane & 15;     // A-row / B-col / C-col within tile
        int lk = lane >> 4;     // k-group (0..3)

        #pragma unroll
        for (int it = 0; it < 16; ++it) {
            int i = it * 256 + tid;          // 0..4095 float4-chunks
            int r = i >> 5;                  // 0..127
            int c4 = (i & 31) << 2;          // col 0,4,...,124
            int grow = row0 + r;
            float4 v = make_float4(0.f, 0.f, 0.f, 0.f);
            if (grow < NN) v = *(const float4*)(x + (size_t)grow * IND + c4);
            unsigned hi01 = (unsigned)bf16_rne(v.x) | ((unsigned)bf16_rne(v.y) << 16);
            unsigned hi23 = (unsigned)bf16_rne(v.z) | ((unsigned)bf16_rne(v.w) << 16);
            int swg = (c4 >> 3) ^ (r & 15);                // 4-bit swizzled 16B granule
            int sidx = r * 128 + swg * 8 + (c4 & 4);       // in shorts
            *(uint2*)(&Ahi[sidx]) = make_uint2(hi01, hi23);
        }
        __syncthreads();

        f32x4 acc[2][9];
        #pragma unroll
        for (int mt = 0; mt < 2; ++mt)
            #pragma unroll
            for (int nt = 0; nt < 9; ++nt) acc[mt][nt] = (f32x4)(0.f);

        #pragma unroll
        for (int ks = 0; ks < 4; ++ks) {
            short8 bh[9];
            #pragma unroll
            for (int nt = 0; nt < 9; ++nt)
                bh[nt] = *(const short8*)(WTf + (((ks * 9 + nt) << 6) + lane) * 8);  // coalesced 1KB
            #pragma unroll
            for (int mt = 0; mt < 2; ++mt) {
                int arow = wave * 32 + mt * 16 + lr;
                int swg = (ks * 4 + lk) ^ lr;              // arow&15 == lr
                short8 ah = *(const short8*)(&Ahi[arow * 128 + swg * 8]);
                #pragma unroll
                for (int nt = 0; nt < 9; ++nt)
                    acc[mt][nt] = __builtin_amdgcn_mfma_f32_16x16x32_bf16(ah, bh[nt], acc[mt][nt], 0, 0, 0);
            }
        }
        #pragma unroll
        for (int mt = 0; mt < 2; ++mt) {
            #pragma unroll
            for (int nt = 0; nt < 9; ++nt) {
                int c = nt * 16 + lr;
                #pragma unroll
                for (int r = 0; r < 4; ++r) {
                    int row = row0 + wave * 32 + mt * 16 + lk * 4 + r;
                    if (row >= NN) continue;
                    float v = acc[mt][nt][r];
                    if (c < 64)       hbf[(size_t)row * TOT + c] = bf16_rne(v);
                    else if (c < 128) res[(size_t)row * TOT + (c - 64)] = v;
                    else if (c < 132) al[(size_t)row * 4 + (c - 128)] = v;
                    else if (c < 136) ar[(size_t)row * 4 + (c - 132)] = v;
                }
            }
        }
    } else {
        // ---------------- binning role (64-node buckets) ----------------
        int* hist = (int*)smem;          // BKT ints
        int* lcur = hist + BKT;          // BKT ints (12.5KB total)
        int cb = blockIdx.x - K1B;
        int stripe = cb & 7;
        int e0 = cb * CHUNKF;
        for (int i = tid; i < BKT; i += 256) hist[i] = 0;
        __syncthreads();
        for (int i = tid; i < CHUNKF; i += 256) {
            int e = e0 + i;
            if (e < NE) atomicAdd(&hist[dst[e] >> 6], 1);
        }
        __syncthreads();
        for (int b = tid; b < BKT; b += 256) {
            int c = hist[b];
            lcur[b] = (c > 0) ? atomicAdd(cursor + b * STRIPES + stripe, c) : 0;
        }
        __syncthreads();
        for (int i = tid; i < CHUNKF; i += 256) {
            int e = e0 + i;
            if (e >= NE) continue;
            int d = dst[e];
            int b = d >> 6;
            int pos = atomicAdd(&lcur[b], 1);
            if (pos < CAPS)
                tmp[(size_t)(b * STRIPES + stripe) * CAPS + pos] =
                    make_int2(src[e] | ((d & 63) << 20), __float_as_int(ew[e]));
        }
    }
}

// kpagg: FUSED permute + aggregate, one block per 64-node bucket, 512 threads
// (round-21 proven fast form: 1563 blocks, ~17KB LDS, 8 waves x 8 nodes).
__global__ __launch_bounds__(512) void kpagg(const int* __restrict__ cursor,
                                             const int2* __restrict__ tmp,
                                             const float* __restrict__ al,
                                             const float* __restrict__ ar,
                                             const unsigned short* __restrict__ hbf,
                                             float* __restrict__ out) {
    __shared__ int hist[65];
    __shared__ int cur[64];
    __shared__ int ns[8];
    __shared__ float4 arl[64];
    __shared__ int lrecS[STRIDE];
    __shared__ unsigned lrecC[STRIDE * 2];
    int tid = threadIdx.x;
    int b = blockIdx.x;
    int node0 = b * 64;

    if (tid < 65) hist[tid] = 0;
    if (tid < 8) ns[tid] = min(cursor[b * STRIPES + tid], CAPS);
    if (tid >= 64 && tid < 128) {
        int l = tid - 64;
        int node = node0 + l;
        arl[l] = (node < NN) ? *(const float4*)(ar + (size_t)node * 4)
                             : make_float4(0.f, 0.f, 0.f, 0.f);
    }
    __syncthreads();

    // pass 1: per-node counts (hist[dlo+1]) over the bucket's 8 stripes
    const int2* tb = tmp + (size_t)b * STRIPES * CAPS;
    for (int j = tid; j < STRIPES * CAPS; j += 512) {
        int s8 = j >> 8;              // CAPS = 256
        int i = j & (CAPS - 1);
        if (i < ns[s8])
            atomicAdd(&hist[(((unsigned)tb[(size_t)s8 * CAPS + i].x) >> 20) + 1], 1);
    }
    __syncthreads();
    // Hillis-Steele scan over hist[0..64] -> exclusive node offsets
    for (int off = 1; off < 65; off <<= 1) {
        int v = 0;
        if (tid < 65 && tid >= off) v = hist[tid - off];
        __syncthreads();
        if (tid < 65) hist[tid] += v;
        __syncthreads();
    }
    if (tid < 64) cur[tid] = hist[tid];
    __syncthreads();

    // pass 2: coef compute + scatter into LDS records
    for (int j = tid; j < STRIPES * CAPS; j += 512) {
        int s8 = j >> 8;
        int i = j & (CAPS - 1);
        if (i >= ns[s8]) continue;
        int2 r = tb[(size_t)s8 * CAPS + i];
        int s = r.x & 0xFFFFF;
        int dlo = ((unsigned)r.x) >> 20;
        float w = __int_as_float(r.y);
        float4 a4 = *(const float4*)(al + (size_t)s * 4);   // L2-resident (1.6MB)
        float4 b4 = arl[dlo];
        float c0 = __expf(lrelu(w * (a4.x + b4.x)));
        float c1 = __expf(lrelu(w * (a4.y + b4.y)));
        float c2 = __expf(lrelu(w * (a4.z + b4.z)));
        float c3 = __expf(lrelu(w * (a4.w + b4.w)));
        int pos = atomicAdd(&cur[dlo], 1);
        if (pos < STRIDE) {
            lrecS[pos] = s;
            lrecC[pos * 2 + 0] = pack_h2(c0, c1);
            lrecC[pos * 2 + 1] = pack_h2(c2, c3);
        }
    }
    __syncthreads();

    // aggregate: 8 waves x 8 nodes each; per wave: 8 record-slots x 8 parts
    int wave = tid >> 6;
    int lane = tid & 63;
    int slot = lane >> 3;
    int part = lane & 7;
    int head = part >> 1;
    int cwo = head >> 1;
    for (int rr = 0; rr < 8; ++rr) {
        int dlo = wave * 8 + rr;
        int node = node0 + dlo;
        if (node >= NN) break;
        int beg = hist[dlo];
        int end = min(hist[dlo + 1], STRIDE);
        beg = min(beg, end);

        float4 acc0 = make_float4(0.f, 0.f, 0.f, 0.f);
        float4 acc1 = make_float4(0.f, 0.f, 0.f, 0.f);
        float den = 0.f;
        for (int p = beg + slot; p < end; p += 8) {
            int s = lrecS[p];
            unsigned cw = lrecC[p * 2 + cwo];
            float c = unpack_h(cw, head & 1);
            den += c;
            uint4 u = *(const uint4*)(hbf + (size_t)s * TOT + part * 8);  // 8 lanes = 128B line
            acc0.x = fmaf(__uint_as_float(u.x << 16),          c, acc0.x);
            acc0.y = fmaf(__uint_as_float(u.x & 0xFFFF0000u),  c, acc0.y);
            acc0.z = fmaf(__uint_as_float(u.y << 16),          c, acc0.z);
            acc0.w = fmaf(__uint_as_float(u.y & 0xFFFF0000u),  c, acc0.w);
            acc1.x = fmaf(__uint_as_float(u.z << 16),          c, acc1.x);
            acc1.y = fmaf(__uint_as_float(u.z & 0xFFFF0000u),  c, acc1.y);
            acc1.z = fmaf(__uint_as_float(u.w << 16),          c, acc1.z);
            acc1.w = fmaf(__uint_as_float(u.w & 0xFFFF0000u),  c, acc1.w);
        }
        #pragma unroll
        for (int off = 8; off <= 32; off <<= 1) {
            acc0.x += __shfl_xor(acc0.x, off);
            acc0.y += __shfl_xor(acc0.y, off);
            acc0.z += __shfl_xor(acc0.z, off);
            acc0.w += __shfl_xor(acc0.w, off);
            acc1.x += __shfl_xor(acc1.x, off);
            acc1.y += __shfl_xor(acc1.y, off);
            acc1.z += __shfl_xor(acc1.z, off);
            acc1.w += __shfl_xor(acc1.w, off);
            den    += __shfl_xor(den, off);
        }
        if (slot == 0) {
            float rinv = (den > 0.f) ? 1.f / den : 0.f;
            float* op = out + (size_t)node * TOT + part * 8;
            float4 r0 = *(const float4*)op;
            float4 r1 = *(const float4*)(op + 4);
            float4 o0, o1;
            o0.x = elu_fast(acc0.x * rinv) + r0.x;
            o0.y = elu_fast(acc0.y * rinv) + r0.y;
            o0.z = elu_fast(acc0.z * rinv) + r0.z;
            o0.w = elu_fast(acc0.w * rinv) + r0.w;
            o1.x = elu_fast(acc1.x * rinv) + r1.x;
            o1.y = elu_fast(acc1.y * rinv) + r1.y;
            o1.z = elu_fast(acc1.z * rinv) + r1.z;
            o1.w = elu_fast(acc1.w * rinv) + r1.w;
            *(float4*)op = o0;
            *(float4*)(op + 4) = o1;
        }
    }
}

extern "C" void kernel_launch(void* const* d_in, const int* in_sizes, int n_in,
                              void* d_out, int out_size, void* d_ws, size_t ws_size,
                              hipStream_t stream) {
    const float* x    = (const float*)d_in[0];
    const int*   ei   = (const int*)d_in[1];
    const float* ew   = (const float*)d_in[2];
    const float* lw   = (const float*)d_in[3];
    const float* attl = (const float*)d_in[4];
    const float* attr = (const float*)d_in[5];
    const float* lrw  = (const float*)d_in[6];
    float* out = (float*)d_out;
    const int* src = ei;
    const int* dst = ei + NE;

    char* w = (char*)d_ws;
    auto alloc = [&](size_t bytes) { char* p = w; w += (bytes + 255) & ~(size_t)255; return p; };
    unsigned short* WTf = (unsigned short*)alloc((size_t)NCOL * 128 * 2);
    unsigned short* hbf = (unsigned short*)alloc((size_t)NN * TOT * 2);
    float* al      = (float*)alloc((size_t)NN * 4 * 4);
    float* ar      = (float*)alloc((size_t)NN * 4 * 4);
    int*   cursor  = (int*)alloc((size_t)BKT * STRIPES * 4);
    int2*  tmp     = (int2*)alloc((size_t)BKT * STRIPES * CAPS * 8);
    size_t needed = (size_t)(w - (char*)d_ws);
    if (ws_size < needed) return;  // fail loudly (validation will catch)

    hipMemsetAsync(cursor, 0, (size_t)BKT * STRIPES * 4, stream);

    k0_wt<<<(NCOL * 128 + 255) / 256, 256, 0, stream>>>(lw, lrw, attl, attr, WTf);
    k1bin<<<K1B + NBINF, 256, 0, stream>>>(x, WTf, hbf, out, al, ar,
                                           src, dst, ew, cursor, tmp);
    kpagg<<<BKT, 512, 0, stream>>>(cursor, tmp, al, ar, hbf, out);
}

// Round 26
// 122.410 us; speedup vs baseline: 1.4719x; 1.0016x over previous
//
#include <hip/hip_runtime.h>
#include <hip/hip_fp16.h>
#include <float.h>

#define NN 100000
#define NE 1600000
#define IND 128
#define NH 4
#define TOT 64
#define NCOL 144                 // 64 h | 64 res | 4 al | 4 ar | 8 pad  (9 x 16)
#define BKT 1563                 // ceil(NN/64): buckets of 64 dst nodes
#define STRIPES 8                // XCD stripes per bucket
#define CAPS 256                 // per (bucket,stripe) record capacity (mean 128, +11 sigma)
#define CHUNKF 4096              // edges per kbin-role block (391 blocks hide under GEMM)
#define NBINF ((NE + CHUNKF - 1) / CHUNKF)   // 391
#define K1B 782                  // k1-role blocks (128 rows each)
#define STRIDE 1280              // records per bucket (mean 1024, +8 sigma)

typedef __attribute__((ext_vector_type(8))) short short8;
typedef __attribute__((ext_vector_type(4))) float f32x4;
typedef __attribute__((ext_vector_type(2))) __fp16 fp16x2;

__device__ __forceinline__ float lrelu(float a) { return a > 0.0f ? a : 0.2f * a; }

__device__ __forceinline__ unsigned short bf16_rne(float f) {
    unsigned u = __float_as_uint(f);
    unsigned r = u + 0x7FFFu + ((u >> 16) & 1u);
    return (unsigned short)(r >> 16);
}
__device__ __forceinline__ float bf16_to_f(unsigned short h) {
    return __uint_as_float(((unsigned)h) << 16);
}
__device__ __forceinline__ unsigned pack_h2(float a, float b) {
    fp16x2 h = __builtin_amdgcn_cvt_pkrtz(a, b);   // v_cvt_pkrtz_f16_f32
    return *(unsigned*)&h;
}
__device__ __forceinline__ float unpack_h(unsigned w, int hi) {
    unsigned short us = hi ? (unsigned short)(w >> 16) : (unsigned short)(w & 0xFFFF);
    __fp16 h = *(__fp16*)&us;
    return (float)h;
}
__device__ __forceinline__ float elu_fast(float a) {
    return a > 0.f ? a : __expf(a) - 1.f;   // hw v_exp vs ~35-inst expm1f
}

// K0: build bf16 weights in MFMA FRAGMENT ORDER:
// WTf[((ks*9 + nt)*64 + lk*16 + lr)*8 + j]  for k = ks*32 + lk*8 + j, c = nt*16 + lr.
__global__ void k0_wt(const float* __restrict__ lw, const float* __restrict__ lrw,
                      const float* __restrict__ attl, const float* __restrict__ attr,
                      unsigned short* __restrict__ WTf) {
    int idx = blockIdx.x * 256 + threadIdx.x;   // NCOL*128 = 18432
    if (idx >= NCOL * 128) return;
    int c = idx >> 7, k = idx & 127;
    float v = 0.f;
    if (c < 64) v = lw[k * 64 + c];
    else if (c < 128) v = lrw[k * 64 + (c - 64)];
    else if (c < 132) {
        int hh = c - 128; float s = 0.f;
        #pragma unroll
        for (int j = 0; j < 16; ++j) s += lw[k * 64 + hh * 16 + j] * attl[hh * 16 + j];
        v = s;
    } else if (c < 136) {
        int hh = c - 132; float s = 0.f;
        #pragma unroll
        for (int j = 0; j < 16; ++j) s += lw[k * 64 + hh * 16 + j] * attr[hh * 16 + j];
        v = s;
    }
    int nt = c >> 4, lr = c & 15;
    int ks = k >> 5, lk = (k >> 3) & 3, j = k & 7;
    WTf[(((ks * 9 + nt) * 64) + lk * 16 + lr) * 8 + j] = bf16_rne(v);
}

// k1bin: FUSED independent stages. Blocks [0,K1B): bf16 MFMA GEMM, 128 rows,
// fragment-ordered B. hbf (c<64) epilogue is LDS-staged with bank-conflict-free
// column swizzle -> fully coalesced 128B-line writes (12.8MB instead of 25.6MB
// of 32B half-sectors). res/al/ar stay direct (full sectors already).
// Blocks [K1B,K1B+NBINF): edge binning into 1563 64-node buckets, CHUNKF=4096.
__global__ __launch_bounds__(256) void k1bin(const float* __restrict__ x,
        const unsigned short* __restrict__ WTf,
        unsigned short* __restrict__ hbf, float* __restrict__ res,
        float* __restrict__ al, float* __restrict__ ar,
        const int* __restrict__ src, const int* __restrict__ dst,
        const float* __restrict__ ew,
        int* __restrict__ cursor, int2* __restrict__ tmp) {
    __shared__ __attribute__((aligned(16))) char smem[32768];
    int tid = threadIdx.x;

    if (blockIdx.x < K1B) {
        // ---------------- GEMM role ----------------
        unsigned short* Ahi = (unsigned short*)smem;   // 128x128 bf16, swizzled
        int lane = tid & 63;
        int wave = tid >> 6;
        int row0 = blockIdx.x * 128;
        int lr = lane & 15;     // A-row / B-col / C-col within tile
        int lk = lane >> 4;     // k-group (0..3)

        #pragma unroll
        for (int it = 0; it < 16; ++it) {
            int i = it * 256 + tid;          // 0..4095 float4-chunks
            int r = i >> 5;                  // 0..127
            int c4 = (i & 31) << 2;          // col 0,4,...,124
            int grow = row0 + r;
            float4 v = make_float4(0.f, 0.f, 0.f, 0.f);
            if (grow < NN) v = *(const float4*)(x + (size_t)grow * IND + c4);
            unsigned hi01 = (unsigned)bf16_rne(v.x) | ((unsigned)bf16_rne(v.y) << 16);
            unsigned hi23 = (unsigned)bf16_rne(v.z) | ((unsigned)bf16_rne(v.w) << 16);
            int swg = (c4 >> 3) ^ (r & 15);                // 4-bit swizzled 16B granule
            int sidx = r * 128 + swg * 8 + (c4 & 4);       // in shorts
            *(uint2*)(&Ahi[sidx]) = make_uint2(hi01, hi23);
        }
        __syncthreads();

        f32x4 acc[2][9];
        #pragma unroll
        for (int mt = 0; mt < 2; ++mt)
            #pragma unroll
            for (int nt = 0; nt < 9; ++nt) acc[mt][nt] = (f32x4)(0.f);

        #pragma unroll
        for (int ks = 0; ks < 4; ++ks) {
            short8 bh[9];
            #pragma unroll
            for (int nt = 0; nt < 9; ++nt)
                bh[nt] = *(const short8*)(WTf + (((ks * 9 + nt) << 6) + lane) * 8);  // coalesced 1KB
            #pragma unroll
            for (int mt = 0; mt < 2; ++mt) {
                int arow = wave * 32 + mt * 16 + lr;
                int swg = (ks * 4 + lk) ^ lr;              // arow&15 == lr
                short8 ah = *(const short8*)(&Ahi[arow * 128 + swg * 8]);
                #pragma unroll
                for (int nt = 0; nt < 9; ++nt)
                    acc[mt][nt] = __builtin_amdgcn_mfma_f32_16x16x32_bf16(ah, bh[nt], acc[mt][nt], 0, 0, 0);
            }
        }
        // epilogue A: res/al/ar direct (full-sector f32 stores)
        #pragma unroll
        for (int mt = 0; mt < 2; ++mt) {
            #pragma unroll
            for (int nt = 4; nt < 9; ++nt) {
                int c = nt * 16 + lr;
                #pragma unroll
                for (int r = 0; r < 4; ++r) {
                    int row = row0 + wave * 32 + mt * 16 + lk * 4 + r;
                    if (row >= NN) continue;
                    float v = acc[mt][nt][r];
                    if (c < 128)      res[(size_t)row * TOT + (c - 64)] = v;
                    else if (c < 132) al[(size_t)row * 4 + (c - 128)] = v;
                    else if (c < 136) ar[(size_t)row * 4 + (c - 132)] = v;
                }
            }
        }
        // epilogue B: hbf (c<64) staged in LDS with conflict-free column swizzle,
        // then one fully coalesced block write.
        __syncthreads();                                   // Ahi reads done; reuse
        unsigned short* Cs = (unsigned short*)smem;        // [128][64] bf16 = 16KB
        #pragma unroll
        for (int mt = 0; mt < 2; ++mt)
            #pragma unroll
            for (int nt = 0; nt < 4; ++nt)
                #pragma unroll
                for (int r = 0; r < 4; ++r) {
                    int row = wave * 32 + mt * 16 + lk * 4 + r;
                    int c = nt * 16 + lr;
                    int cs = c ^ (((row >> 2) & 3) << 4);  // lk groups -> disjoint banks
                    Cs[row * 64 + cs] = bf16_rne(acc[mt][nt][r]);
                }
        __syncthreads();
        int nrows = min(128, NN - row0);
        int nchunk = nrows * 8;                            // 16B chunks (8 per row)
        uint4* dstp = (uint4*)(hbf + (size_t)row0 * TOT);
        for (int i = tid; i < nchunk; i += 256) {
            int row = i >> 3;
            int g = i & 7;
            int gp = g ^ (((row >> 2) & 3) << 1);          // inverse of column swizzle
            dstp[i] = *(const uint4*)(&Cs[row * 64 + gp * 8]);
        }
    } else {
        // ---------------- binning role (64-node buckets) ----------------
        int* hist = (int*)smem;          // BKT ints
        int* lcur = hist + BKT;          // BKT ints (12.5KB total)
        int cb = blockIdx.x - K1B;
        int stripe = cb & 7;
        int e0 = cb * CHUNKF;
        for (int i = tid; i < BKT; i += 256) hist[i] = 0;
        __syncthreads();
        for (int i = tid; i < CHUNKF; i += 256) {
            int e = e0 + i;
            if (e < NE) atomicAdd(&hist[dst[e] >> 6], 1);
        }
        __syncthreads();
        for (int b = tid; b < BKT; b += 256) {
            int c = hist[b];
            lcur[b] = (c > 0) ? atomicAdd(cursor + b * STRIPES + stripe, c) : 0;
        }
        __syncthreads();
        for (int i = tid; i < CHUNKF; i += 256) {
            int e = e0 + i;
            if (e >= NE) continue;
            int d = dst[e];
            int b = d >> 6;
            int pos = atomicAdd(&lcur[b], 1);
            if (pos < CAPS)
                tmp[(size_t)(b * STRIPES + stripe) * CAPS + pos] =
                    make_int2(src[e] | ((d & 63) << 20), __float_as_int(ew[e]));
        }
    }
}

// kpagg: FUSED permute + aggregate, one block per 64-node bucket, 512 threads
// (1563 blocks, ~17KB LDS, 8 waves x 8 nodes; 8 record-slots x 8 parts).
__global__ __launch_bounds__(512) void kpagg(const int* __restrict__ cursor,
                                             const int2* __restrict__ tmp,
                                             const float* __restrict__ al,
                                             const float* __restrict__ ar,
                                             const unsigned short* __restrict__ hbf,
                                             float* __restrict__ out) {
    __shared__ int hist[65];
    __shared__ int cur[64];
    __shared__ int ns[8];
    __shared__ float4 arl[64];
    __shared__ int lrecS[STRIDE];
    __shared__ unsigned lrecC[STRIDE * 2];
    int tid = threadIdx.x;
    int b = blockIdx.x;
    int node0 = b * 64;

    if (tid < 65) hist[tid] = 0;
    if (tid < 8) ns[tid] = min(cursor[b * STRIPES + tid], CAPS);
    if (tid >= 64 && tid < 128) {
        int l = tid - 64;
        int node = node0 + l;
        arl[l] = (node < NN) ? *(const float4*)(ar + (size_t)node * 4)
                             : make_float4(0.f, 0.f, 0.f, 0.f);
    }
    __syncthreads();

    // pass 1: per-node counts (hist[dlo+1]) over the bucket's 8 stripes
    const int2* tb = tmp + (size_t)b * STRIPES * CAPS;
    for (int j = tid; j < STRIPES * CAPS; j += 512) {
        int s8 = j >> 8;              // CAPS = 256
        int i = j & (CAPS - 1);
        if (i < ns[s8])
            atomicAdd(&hist[(((unsigned)tb[(size_t)s8 * CAPS + i].x) >> 20) + 1], 1);
    }
    __syncthreads();
    // Hillis-Steele scan over hist[0..64] -> exclusive node offsets
    for (int off = 1; off < 65; off <<= 1) {
        int v = 0;
        if (tid < 65 && tid >= off) v = hist[tid - off];
        __syncthreads();
        if (tid < 65) hist[tid] += v;
        __syncthreads();
    }
    if (tid < 64) cur[tid] = hist[tid];
    __syncthreads();

    // pass 2: coef compute + scatter into LDS records
    for (int j = tid; j < STRIPES * CAPS; j += 512) {
        int s8 = j >> 8;
        int i = j & (CAPS - 1);
        if (i >= ns[s8]) continue;
        int2 r = tb[(size_t)s8 * CAPS + i];
        int s = r.x & 0xFFFFF;
        int dlo = ((unsigned)r.x) >> 20;
        float w = __int_as_float(r.y);
        float4 a4 = *(const float4*)(al + (size_t)s * 4);   // L2-resident (1.6MB)
        float4 b4 = arl[dlo];
        float c0 = __expf(lrelu(w * (a4.x + b4.x)));
        float c1 = __expf(lrelu(w * (a4.y + b4.y)));
        float c2 = __expf(lrelu(w * (a4.z + b4.z)));
        float c3 = __expf(lrelu(w * (a4.w + b4.w)));
        int pos = atomicAdd(&cur[dlo], 1);
        if (pos < STRIDE) {
            lrecS[pos] = s;
            lrecC[pos * 2 + 0] = pack_h2(c0, c1);
            lrecC[pos * 2 + 1] = pack_h2(c2, c3);
        }
    }
    __syncthreads();

    // aggregate: 8 waves x 8 nodes each; per wave: 8 record-slots x 8 parts
    int wave = tid >> 6;
    int lane = tid & 63;
    int slot = lane >> 3;
    int part = lane & 7;
    int head = part >> 1;
    int cwo = head >> 1;
    for (int rr = 0; rr < 8; ++rr) {
        int dlo = wave * 8 + rr;
        int node = node0 + dlo;
        if (node >= NN) break;
        int beg = hist[dlo];
        int end = min(hist[dlo + 1], STRIDE);
        beg = min(beg, end);

        float4 acc0 = make_float4(0.f, 0.f, 0.f, 0.f);
        float4 acc1 = make_float4(0.f, 0.f, 0.f, 0.f);
        float den = 0.f;
        for (int p = beg + slot; p < end; p += 8) {
            int s = lrecS[p];
            unsigned cw = lrecC[p * 2 + cwo];
            float c = unpack_h(cw, head & 1);
            den += c;
            uint4 u = *(const uint4*)(hbf + (size_t)s * TOT + part * 8);  // 8 lanes = 128B line
            acc0.x = fmaf(__uint_as_float(u.x << 16),          c, acc0.x);
            acc0.y = fmaf(__uint_as_float(u.x & 0xFFFF0000u),  c, acc0.y);
            acc0.z = fmaf(__uint_as_float(u.y << 16),          c, acc0.z);
            acc0.w = fmaf(__uint_as_float(u.y & 0xFFFF0000u),  c, acc0.w);
            acc1.x = fmaf(__uint_as_float(u.z << 16),          c, acc1.x);
            acc1.y = fmaf(__uint_as_float(u.z & 0xFFFF0000u),  c, acc1.y);
            acc1.z = fmaf(__uint_as_float(u.w << 16),          c, acc1.z);
            acc1.w = fmaf(__uint_as_float(u.w & 0xFFFF0000u),  c, acc1.w);
        }
        #pragma unroll
        for (int off = 8; off <= 32; off <<= 1) {
            acc0.x += __shfl_xor(acc0.x, off);
            acc0.y += __shfl_xor(acc0.y, off);
            acc0.z += __shfl_xor(acc0.z, off);
            acc0.w += __shfl_xor(acc0.w, off);
            acc1.x += __shfl_xor(acc1.x, off);
            acc1.y += __shfl_xor(acc1.y, off);
            acc1.z += __shfl_xor(acc1.z, off);
            acc1.w += __shfl_xor(acc1.w, off);
            den    += __shfl_xor(den, off);
        }
        if (slot == 0) {
            float rinv = (den > 0.f) ? 1.f / den : 0.f;
            float* op = out + (size_t)node * TOT + part * 8;
            float4 r0 = *(const float4*)op;
            float4 r1 = *(const float4*)(op + 4);
            float4 o0, o1;
            o0.x = elu_fast(acc0.x * rinv) + r0.x;
            o0.y = elu_fast(acc0.y * rinv) + r0.y;
            o0.z = elu_fast(acc0.z * rinv) + r0.z;
            o0.w = elu_fast(acc0.w * rinv) + r0.w;
            o1.x = elu_fast(acc1.x * rinv) + r1.x;
            o1.y = elu_fast(acc1.y * rinv) + r1.y;
            o1.z = elu_fast(acc1.z * rinv) + r1.z;
            o1.w = elu_fast(acc1.w * rinv) + r1.w;
            *(float4*)op = o0;
            *(float4*)(op + 4) = o1;
        }
    }
}

extern "C" void kernel_launch(void* const* d_in, const int* in_sizes, int n_in,
                              void* d_out, int out_size, void* d_ws, size_t ws_size,
                              hipStream_t stream) {
    const float* x    = (const float*)d_in[0];
    const int*   ei   = (const int*)d_in[1];
    const float* ew   = (const float*)d_in[2];
    const float* lw   = (const float*)d_in[3];
    const float* attl = (const float*)d_in[4];
    const float* attr = (const float*)d_in[5];
    const float* lrw  = (const float*)d_in[6];
    float* out = (float*)d_out;
    const int* src = ei;
    const int* dst = ei + NE;

    char* w = (char*)d_ws;
    auto alloc = [&](size_t bytes) { char* p = w; w += (bytes + 255) & ~(size_t)255; return p; };
    unsigned short* WTf = (unsigned short*)alloc((size_t)NCOL * 128 * 2);
    unsigned short* hbf = (unsigned short*)alloc((size_t)NN * TOT * 2);
    float* al      = (float*)alloc((size_t)NN * 4 * 4);
    float* ar      = (float*)alloc((size_t)NN * 4 * 4);
    int*   cursor  = (int*)alloc((size_t)BKT * STRIPES * 4);
    int2*  tmp     = (int2*)alloc((size_t)BKT * STRIPES * CAPS * 8);
    size_t needed = (size_t)(w - (char*)d_ws);
    if (ws_size < needed) return;  // fail loudly (validation will catch)

    hipMemsetAsync(cursor, 0, (size_t)BKT * STRIPES * 4, stream);

    k0_wt<<<(NCOL * 128 + 255) / 256, 256, 0, stream>>>(lw, lrw, attl, attr, WTf);
    k1bin<<<K1B + NBINF, 256, 0, stream>>>(x, WTf, hbf, out, al, ar,
                                           src, dst, ew, cursor, tmp);
    kpagg<<<BKT, 512, 0, stream>>>(cursor, tmp, al, ar, hbf, out);
}